// Round 1
// baseline (463.449 us; speedup 1.0000x reference)
//
#include <hip/hip_runtime.h>
#include <hip/hip_cooperative_groups.h>
#include <math.h>

namespace cg = cooperative_groups;

#define NN 8192
#define FIN 512
#define FOUT 256
#define GRID 512         // cooperative grid: 512 blocks x 256 thr, 16 rows/block
#define NU 8             // rotated u copies (atomic contention control)

// Math: softmax(s_i + d_j, axis=1) — row-constant s_i cancels, so
//   out[i,:] = (sum_j exp(d_j) h[j,:]) / (sum_j exp(d_j))   for ALL i.
// With d = x @ g, g = W^T a_dst, and v = W @ (sum_j w_j x_j), h is never
// materialized and x is read exactly once.
// Shift-0 exp is safe: |g| ~ 0.14, |x_row| ~ 23 => |d| < ~3. Shift
// invariance makes this identical to max-subtracted softmax.
//
// THIS VERSION: single cooperative kernel. Previous 4-dispatch version
// measured 322.8 us = 4 x 80.7 us/dispatch while intrinsic work is ~25 MB
// of traffic (~6 us) — per-dispatch fixed cost dominated. Two grid.sync()s
// replace three kernel boundaries.

__global__ __launch_bounds__(256, 2) void gat_fused_all(
    const float* __restrict__ x,
    const float* __restrict__ W,
    const float* __restrict__ a_dst,
    float* __restrict__ out,
    float* __restrict__ g,
    float* __restrict__ u8,
    float* __restrict__ S)
{
    cg::grid_group gg = cg::this_grid();

    __shared__ float us[4][FIN];    // 8 KB: phase A scratch, phase B partials, phase C u
    __shared__ float sred[4];
    __shared__ float vsh[FOUT];     // 1 KB: phase C result v

    const int tid  = threadIdx.x;
    const int bid  = blockIdx.x;
    const int lane = tid & 63;
    const int wave = tid >> 6;      // 0..3
    const int r0   = bid * 16;

    // ---------------- Phase A: g[k] = sum_c W[c,k]*a_dst[c]; zero u8,S ----
    if (bid < 8) {
        const int zi = bid * 256 + tid;              // 2048 float2 = 4096 floats
        ((float2*)u8)[zi] = make_float2(0.f, 0.f);
        if (zi == 0) *S = 0.f;

        const int k = bid * 64 + lane;               // 0..511
        float s = 0.f;
        #pragma unroll 8
        for (int c = wave * 64; c < wave * 64 + 64; ++c)
            s = fmaf(W[(size_t)c * FIN + k], a_dst[c], s);
        us[wave][lane] = s;
        __syncthreads();
        if (wave == 0) g[k] = us[0][lane] + us[1][lane] + us[2][lane] + us[3][lane];
    }
    gg.sync();   // g, u8=0, S=0 visible device-wide

    // ---------------- Phase B: w = exp(x.g); u-partials -> atomics --------
    const float4* g4 = (const float4*)g;
    const float4 g0 = g4[lane], g1 = g4[lane + 64];

    float4 xa[4], xb[4];
    float w[4];
    #pragma unroll
    for (int rr = 0; rr < 4; ++rr) {
        const float4* xr = (const float4*)(x + (size_t)(r0 + wave * 4 + rr) * FIN);
        xa[rr] = xr[lane];
        xb[rr] = xr[lane + 64];
        float s = xa[rr].x * g0.x + xa[rr].y * g0.y + xa[rr].z * g0.z + xa[rr].w * g0.w
                + xb[rr].x * g1.x + xb[rr].y * g1.y + xb[rr].z * g1.z + xb[rr].w * g1.w;
        #pragma unroll
        for (int off = 32; off; off >>= 1) s += __shfl_xor(s, off);
        w[rr] = __expf(s);          // shift-0: see header comment
    }
    if (lane == 0) sred[wave] = w[0] + w[1] + w[2] + w[3];

    float4 pa = make_float4(0.f, 0.f, 0.f, 0.f);
    float4 pb = make_float4(0.f, 0.f, 0.f, 0.f);
    #pragma unroll
    for (int rr = 0; rr < 4; ++rr) {
        pa.x = fmaf(w[rr], xa[rr].x, pa.x); pa.y = fmaf(w[rr], xa[rr].y, pa.y);
        pa.z = fmaf(w[rr], xa[rr].z, pa.z); pa.w = fmaf(w[rr], xa[rr].w, pa.w);
        pb.x = fmaf(w[rr], xb[rr].x, pb.x); pb.y = fmaf(w[rr], xb[rr].y, pb.y);
        pb.z = fmaf(w[rr], xb[rr].z, pb.z); pb.w = fmaf(w[rr], xb[rr].w, pb.w);
    }
    ((float4*)&us[wave][0])[lane]    = pa;
    ((float4*)&us[wave][FOUT])[lane] = pb;
    __syncthreads();

    {
        float* ub = u8 + (size_t)(bid & (NU - 1)) * FIN;
        float v0 = us[0][tid]       + us[1][tid]       + us[2][tid]       + us[3][tid];
        float v1 = us[0][tid + 256] + us[1][tid + 256] + us[2][tid + 256] + us[3][tid + 256];
        atomicAdd(&ub[tid], v0);
        atomicAdd(&ub[tid + 256], v1);
        if (tid == 0) atomicAdd(S, sred[0] + sred[1] + sred[2] + sred[3]);
    }
    gg.sync();   // u8, S complete device-wide

    // ---------------- Phase C: redundant per-block v = (W.u)/S ------------
    {
        float a0 = 0.f, a1 = 0.f;
        #pragma unroll
        for (int i = 0; i < NU; ++i) {
            a0 += u8[(size_t)i * FIN + tid];
            a1 += u8[(size_t)i * FIN + tid + 256];
        }
        us[0][tid]       = a0;      // u lives in us[0][0..511]
        us[0][tid + 256] = a1;
    }
    __syncthreads();

    {
        const float rS = 1.f / (*S);
        const float4* u4 = (const float4*)&us[0][0];
        const float4* wr = (const float4*)(W + (size_t)tid * FIN);  // row c = tid
        float s = 0.f;
        #pragma unroll 16
        for (int i = 0; i < FIN / 4; ++i) {
            const float4 wv = wr[i];
            const float4 uv = u4[i];          // LDS broadcast, conflict-free
            s += wv.x * uv.x + wv.y * uv.y + wv.z * uv.z + wv.w * uv.w;
        }
        vsh[tid] = s * rS;
    }
    __syncthreads();

    // ---------------- Phase D: broadcast 16 rows of out -------------------
    {
        const float4* v4 = (const float4*)vsh;            // 64 float4 per row
        float4* ob = (float4*)out + (size_t)r0 * (FOUT / 4);
        #pragma unroll
        for (int q = 0; q < 4; ++q) {
            const int fi = q * 256 + tid;                 // 0..1023
            ob[fi] = v4[fi & 63];
        }
    }
}

// ===========================================================================
// Fallback path (original 4-dispatch version) — used only if the cooperative
// launch is rejected by the runtime.
// ===========================================================================
__global__ __launch_bounds__(256) void compute_g(const float* __restrict__ W,
                                                 const float* __restrict__ a_dst,
                                                 float* __restrict__ g,
                                                 float* __restrict__ u8,
                                                 float* __restrict__ S) {
    __shared__ float red[4][64];
    const int tid = threadIdx.x;
    const int zi = blockIdx.x * 256 + tid;
    ((float2*)u8)[zi] = make_float2(0.f, 0.f);
    if (zi == 0) *S = 0.f;
    const int kl = tid & 63;
    const int cp = tid >> 6;
    const int k = blockIdx.x * 64 + kl;
    float s = 0.f;
    #pragma unroll 8
    for (int c = cp * 64; c < cp * 64 + 64; ++c)
        s = fmaf(W[(size_t)c * FIN + k], a_dst[c], s);
    red[cp][kl] = s;
    __syncthreads();
    if (cp == 0) g[k] = red[0][kl] + red[1][kl] + red[2][kl] + red[3][kl];
}

__global__ __launch_bounds__(256) void fused_pass(const float* __restrict__ x,
                                                  const float* __restrict__ g,
                                                  float* __restrict__ u8,
                                                  float* __restrict__ S) {
    __shared__ float us[4][FIN];
    __shared__ float sred[4];
    const int tid = threadIdx.x;
    const int lane = tid & 63;
    const int wave = tid >> 6;
    const int r0 = blockIdx.x * 16;
    const float4* g4 = (const float4*)g;
    const float4 g0 = g4[lane], g1 = g4[lane + 64];
    float4 xa[4], xb[4];
    float w[4];
    #pragma unroll
    for (int rr = 0; rr < 4; ++rr) {
        const float4* xr = (const float4*)(x + (size_t)(r0 + wave * 4 + rr) * FIN);
        xa[rr] = xr[lane];
        xb[rr] = xr[lane + 64];
        float s = xa[rr].x * g0.x + xa[rr].y * g0.y + xa[rr].z * g0.z + xa[rr].w * g0.w
                + xb[rr].x * g1.x + xb[rr].y * g1.y + xb[rr].z * g1.z + xb[rr].w * g1.w;
        #pragma unroll
        for (int off = 32; off; off >>= 1) s += __shfl_xor(s, off);
        w[rr] = __expf(s);
    }
    if (lane == 0) sred[wave] = w[0] + w[1] + w[2] + w[3];
    float4 pa = make_float4(0.f, 0.f, 0.f, 0.f);
    float4 pb = make_float4(0.f, 0.f, 0.f, 0.f);
    #pragma unroll
    for (int rr = 0; rr < 4; ++rr) {
        pa.x = fmaf(w[rr], xa[rr].x, pa.x); pa.y = fmaf(w[rr], xa[rr].y, pa.y);
        pa.z = fmaf(w[rr], xa[rr].z, pa.z); pa.w = fmaf(w[rr], xa[rr].w, pa.w);
        pb.x = fmaf(w[rr], xb[rr].x, pb.x); pb.y = fmaf(w[rr], xb[rr].y, pb.y);
        pb.z = fmaf(w[rr], xb[rr].z, pb.z); pb.w = fmaf(w[rr], xb[rr].w, pb.w);
    }
    ((float4*)&us[wave][0])[lane] = pa;
    ((float4*)&us[wave][FOUT])[lane] = pb;
    __syncthreads();
    float* ub = u8 + (size_t)(blockIdx.x & (NU - 1)) * FIN;
    float v0 = us[0][tid] + us[1][tid] + us[2][tid] + us[3][tid];
    float v1 = us[0][tid + 256] + us[1][tid + 256] + us[2][tid + 256] + us[3][tid + 256];
    atomicAdd(&ub[tid], v0);
    atomicAdd(&ub[tid + 256], v1);
    if (tid == 0) atomicAdd(S, sred[0] + sred[1] + sred[2] + sred[3]);
}

__global__ __launch_bounds__(256) void compute_v(const float* __restrict__ W,
                                                 const float* __restrict__ u8,
                                                 const float* __restrict__ S,
                                                 float* __restrict__ vs) {
    __shared__ float us[FIN];
    const int tid = threadIdx.x;
    float a0 = 0.f, a1 = 0.f;
    #pragma unroll
    for (int i = 0; i < NU; ++i) {
        a0 += u8[(size_t)i * FIN + tid];
        a1 += u8[(size_t)i * FIN + tid + 256];
    }
    us[tid] = a0;
    us[tid + 256] = a1;
    __syncthreads();
    const int lane = tid & 63;
    const int wave = tid >> 6;
    const int c = blockIdx.x * 4 + wave;
    const float4* wr = (const float4*)(W + (size_t)c * FIN);
    const float4* uv = (const float4*)us;
    float4 w0 = wr[lane], w1 = wr[lane + 64];
    float4 u0 = uv[lane], u1 = uv[lane + 64];
    float s = w0.x * u0.x + w0.y * u0.y + w0.z * u0.z + w0.w * u0.w
            + w1.x * u1.x + w1.y * u1.y + w1.z * u1.z + w1.w * u1.w;
    #pragma unroll
    for (int off = 32; off; off >>= 1) s += __shfl_xor(s, off);
    if (lane == 0) vs[c] = s / *S;
}

__global__ __launch_bounds__(256) void broadcast_out(const float* __restrict__ vs,
                                                     float* __restrict__ out) {
    const int idx = blockIdx.x * 256 + threadIdx.x;
    float4 vv = ((const float4*)vs)[idx & 63];
    ((float4*)out)[idx] = vv;
}

extern "C" void kernel_launch(void* const* d_in, const int* in_sizes, int n_in,
                              void* d_out, int out_size, void* d_ws, size_t ws_size,
                              hipStream_t stream) {
    const float* x = (const float*)d_in[0];
    // d_in[1] = adj — unused by the reference math (softmax cancellation)
    const float* W = (const float*)d_in[2];
    const float* a = (const float*)d_in[3];
    const float* a_dst = a + FOUT;
    float* out = (float*)d_out;

    float* ws = (float*)d_ws;
    float* g  = ws;                    // 512
    float* u8 = ws + 512;              // NU*512 = 4096
    float* S  = ws + 512 + NU * FIN;   // 1 (+pad)
    float* vs = S + 16;                // 256 (fallback only)

    void* args[] = {(void*)&x, (void*)&W, (void*)&a_dst, (void*)&out,
                    (void*)&g, (void*)&u8, (void*)&S};
    hipError_t err = hipLaunchCooperativeKernel(
        reinterpret_cast<void*>(gat_fused_all), dim3(GRID), dim3(256),
        args, 0, stream);

    if (err != hipSuccess) {
        // fallback: original 4-dispatch path
        compute_g<<<8, 256, 0, stream>>>(W, a_dst, g, u8, S);
        fused_pass<<<GRID, 256, 0, stream>>>(x, g, u8, S);
        compute_v<<<FOUT / 4, 256, 0, stream>>>(W, u8, S, vs);
        broadcast_out<<<(NN * FOUT / 4) / 256, 256, 0, stream>>>(vs, out);
    }
}

// Round 2
// 323.849 us; speedup vs baseline: 1.4311x; 1.4311x over previous
//
#include <hip/hip_runtime.h>
#include <math.h>

#define NN 8192
#define FIN 512
#define FOUT 256
#define FBLK 512          // blocks in fused pass; 16 rows each
#define NU 8              // rotated u copies (atomic contention control)

// Math: softmax(s_i + d_j, axis=1) — row-constant s_i cancels, so
//   out[i,:] = (sum_j exp(d_j) h[j,:]) / (sum_j exp(d_j))   for ALL i.
// With d = x @ g, g = W^T a_dst, and v = W @ (sum_j w_j x_j), h is never
// materialized and x is read exactly once.
// Shift-0 exp is safe here: |g| ~ 0.14, |x_row| ~ 23  =>  |d| < ~3,
// exp range [e-3, e3] — no overflow/underflow possible (shift invariance
// means the result is mathematically identical to max-subtracted softmax).
//
// SESSION NOTE (round 1 post-mortem): dur_us ≈ 322 µs is the harness floor —
// two 1-GiB poison fills per timed iteration at ~160 µs each (6.7 TB/s,
// HBM-write ceiling). Our 4 kernels total ~2-3 µs. A cooperative single-
// kernel fusion REGRESSED to 463 µs (grid.sync cross-XCD drain + redundant
// phase C). Do not re-attempt dispatch fusion; kernel time is ~1% of dur_us.

// ---------------------------------------------------------------------------
// K1: g[k] = sum_c W[c,k]*a_dst[c]  (8 blocks x 256). Also zeros u8 and S.
// ---------------------------------------------------------------------------
__global__ __launch_bounds__(256) void compute_g(const float* __restrict__ W,
                                                 const float* __restrict__ a_dst,
                                                 float* __restrict__ g,
                                                 float* __restrict__ u8,
                                                 float* __restrict__ S) {
    __shared__ float red[4][64];
    const int tid = threadIdx.x;

    // zero the NU*FIN u-copies (8 blocks x 256 thr x 2 floats = 4096)
    const int zi = blockIdx.x * 256 + tid;
    ((float2*)u8)[zi] = make_float2(0.f, 0.f);
    if (zi == 0) *S = 0.f;

    const int kl = tid & 63;
    const int cp = tid >> 6;            // 0..3
    const int k = blockIdx.x * 64 + kl; // 0..511
    float s = 0.f;
    #pragma unroll 8
    for (int c = cp * 64; c < cp * 64 + 64; ++c)
        s = fmaf(W[(size_t)c * FIN + k], a_dst[c], s);
    red[cp][kl] = s;
    __syncthreads();
    if (cp == 0) g[k] = red[0][kl] + red[1][kl] + red[2][kl] + red[3][kl];
}

// ---------------------------------------------------------------------------
// K2: fused pass. 512 blocks x 256 thr (4 waves), 16 rows/block.
// Each wave owns 4 rows; lane l holds cols [4l..4l+3] and [256+4l..259+4l]
// of each of its rows IN REGISTERS (8 float4/lane). Computes d via butterfly
// reduce, w = exp(d), per-wave weighted column partials, LDS cross-wave
// reduce, then atomicAdd into u8[blockIdx&7][*] and S.
// ---------------------------------------------------------------------------
__global__ __launch_bounds__(256) void fused_pass(const float* __restrict__ x,
                                                  const float* __restrict__ g,
                                                  float* __restrict__ u8,
                                                  float* __restrict__ S) {
    __shared__ float us[4][FIN];
    __shared__ float sred[4];
    const int tid = threadIdx.x;
    const int lane = tid & 63;
    const int wave = tid >> 6;          // 0..3
    const int r0 = blockIdx.x * 16;

    const float4* g4 = (const float4*)g;
    const float4 g0 = g4[lane], g1 = g4[lane + 64];

    float4 xa[4], xb[4];
    float w[4];
    #pragma unroll
    for (int rr = 0; rr < 4; ++rr) {
        const float4* xr = (const float4*)(x + (size_t)(r0 + wave * 4 + rr) * FIN);
        xa[rr] = xr[lane];
        xb[rr] = xr[lane + 64];
        float s = xa[rr].x * g0.x + xa[rr].y * g0.y + xa[rr].z * g0.z + xa[rr].w * g0.w
                + xb[rr].x * g1.x + xb[rr].y * g1.y + xb[rr].z * g1.z + xb[rr].w * g1.w;
        #pragma unroll
        for (int off = 32; off; off >>= 1) s += __shfl_xor(s, off);
        w[rr] = __expf(s);              // shift-0: see header comment
    }
    if (lane == 0) sred[wave] = w[0] + w[1] + w[2] + w[3];

    float4 pa = make_float4(0.f, 0.f, 0.f, 0.f);
    float4 pb = make_float4(0.f, 0.f, 0.f, 0.f);
    #pragma unroll
    for (int rr = 0; rr < 4; ++rr) {
        pa.x = fmaf(w[rr], xa[rr].x, pa.x); pa.y = fmaf(w[rr], xa[rr].y, pa.y);
        pa.z = fmaf(w[rr], xa[rr].z, pa.z); pa.w = fmaf(w[rr], xa[rr].w, pa.w);
        pb.x = fmaf(w[rr], xb[rr].x, pb.x); pb.y = fmaf(w[rr], xb[rr].y, pb.y);
        pb.z = fmaf(w[rr], xb[rr].z, pb.z); pb.w = fmaf(w[rr], xb[rr].w, pb.w);
    }
    ((float4*)&us[wave][0])[lane] = pa;
    ((float4*)&us[wave][FOUT])[lane] = pb;
    __syncthreads();

    float* ub = u8 + (size_t)(blockIdx.x & (NU - 1)) * FIN;
    float v0 = us[0][tid] + us[1][tid] + us[2][tid] + us[3][tid];
    float v1 = us[0][tid + 256] + us[1][tid + 256] + us[2][tid + 256] + us[3][tid + 256];
    atomicAdd(&ub[tid], v0);
    atomicAdd(&ub[tid + 256], v1);
    if (tid == 0) atomicAdd(S, sred[0] + sred[1] + sred[2] + sred[3]);
}

// ---------------------------------------------------------------------------
// K3: vs[c] = (W[c,:] . u) / S  where u = sum of the NU copies.
//     64 blocks x 256 thr; 1 wave per c, 4 c's per block.
// ---------------------------------------------------------------------------
__global__ __launch_bounds__(256) void compute_v(const float* __restrict__ W,
                                                 const float* __restrict__ u8,
                                                 const float* __restrict__ S,
                                                 float* __restrict__ vs) {
    __shared__ float us[FIN];
    const int tid = threadIdx.x;
    float a0 = 0.f, a1 = 0.f;
    #pragma unroll
    for (int i = 0; i < NU; ++i) {
        a0 += u8[(size_t)i * FIN + tid];
        a1 += u8[(size_t)i * FIN + tid + 256];
    }
    us[tid] = a0;
    us[tid + 256] = a1;
    __syncthreads();

    const int lane = tid & 63;
    const int wave = tid >> 6;
    const int c = blockIdx.x * 4 + wave;
    const float4* wr = (const float4*)(W + (size_t)c * FIN);
    const float4* uv = (const float4*)us;
    float4 w0 = wr[lane], w1 = wr[lane + 64];
    float4 u0 = uv[lane], u1 = uv[lane + 64];
    float s = w0.x * u0.x + w0.y * u0.y + w0.z * u0.z + w0.w * u0.w
            + w1.x * u1.x + w1.y * u1.y + w1.z * u1.z + w1.w * u1.w;
    #pragma unroll
    for (int off = 32; off; off >>= 1) s += __shfl_xor(s, off);
    if (lane == 0) vs[c] = s / *S;
}

// ---------------------------------------------------------------------------
// K4: out[i,:] = vs  (all rows identical; pure 8 MB store, full device)
// ---------------------------------------------------------------------------
__global__ __launch_bounds__(256) void broadcast_out(const float* __restrict__ vs,
                                                     float* __restrict__ out) {
    const int idx = blockIdx.x * 256 + threadIdx.x;  // float4 index
    float4 vv = ((const float4*)vs)[idx & 63];       // 64 float4 per row
    ((float4*)out)[idx] = vv;
}

extern "C" void kernel_launch(void* const* d_in, const int* in_sizes, int n_in,
                              void* d_out, int out_size, void* d_ws, size_t ws_size,
                              hipStream_t stream) {
    const float* x = (const float*)d_in[0];
    // d_in[1] = adj — unused by the reference math (softmax cancellation)
    const float* W = (const float*)d_in[2];
    const float* a = (const float*)d_in[3];
    float* out = (float*)d_out;

    float* ws = (float*)d_ws;
    float* g  = ws;                    // 512
    float* u8 = ws + 512;              // NU*512 = 4096
    float* S  = ws + 512 + NU * FIN;   // 1 (+pad)
    float* vs = S + 16;                // 256

    compute_g<<<8, 256, 0, stream>>>(W, a + FOUT, g, u8, S);
    fused_pass<<<FBLK, 256, 0, stream>>>(x, g, u8, S);
    compute_v<<<FOUT / 4, 256, 0, stream>>>(W, u8, S, vs);
    broadcast_out<<<(NN * FOUT / 4) / 256, 256, 0, stream>>>(vs, out);
}